// Round 3
// baseline (349.554 us; speedup 1.0000x reference)
//
#include <hip/hip_runtime.h>
#include <math.h>

#define NE 8      // experts
#define ND 512    // features
#define NH 2048   // hidden
#define NT 2048   // tokens = B*S

typedef __attribute__((ext_vector_type(8))) short short8;   // 8 bf16 = 4 VGPRs
typedef __attribute__((ext_vector_type(4))) float f32x4;    // MFMA accumulator

#define GLL(g, d) __builtin_amdgcn_global_load_lds( \
    (const __attribute__((address_space(1))) void*)(g), \
    (__attribute__((address_space(3))) void*)(d), 16, 0, 0)

__device__ __forceinline__ unsigned short f2bf(float x) {
    unsigned int u = __builtin_bit_cast(unsigned int, x);
    u += 0x7FFFu + ((u >> 16) & 1u);            // round-to-nearest-even
    return (unsigned short)(u >> 16);
}

__device__ __forceinline__ short8 neg8(short8 v) {
    int4 u = __builtin_bit_cast(int4, v);
    u.x ^= 0x80008000; u.y ^= 0x80008000; u.z ^= 0x80008000; u.w ^= 0x80008000;
    return __builtin_bit_cast(short8, u);
}

__device__ __forceinline__ short8 lds8(const unsigned short* p) {
    return *(const short8*)p;
}

// ---------------- gating (fp32, exact argmax semantics) ----------------
__global__ __launch_bounds__(256) void gate_kernel(
    const float* __restrict__ xr, const float* __restrict__ xi,
    const float* __restrict__ gW, const float* __restrict__ gb,
    float* __restrict__ gate_w,
    int* __restrict__ counts, int* __restrict__ tok_list)
{
    int t = blockIdx.x;
    int tid = threadIdx.x;
    const float* xrt = xr + (size_t)t * ND;
    const float* xit = xi + (size_t)t * ND;

    float acc[NE] = {0,0,0,0,0,0,0,0};
    for (int r = tid; r < 2 * ND; r += 256) {
        int d = r & (ND - 1);
        float a = xrt[d], b = xit[d];
        float v = (r < ND) ? sqrtf(a * a + b * b) : atan2f(b, a);
        const float4* g = (const float4*)(gW + (size_t)r * NE);
        float4 g0 = g[0], g1 = g[1];
        acc[0] += v * g0.x; acc[1] += v * g0.y; acc[2] += v * g0.z; acc[3] += v * g0.w;
        acc[4] += v * g1.x; acc[5] += v * g1.y; acc[6] += v * g1.z; acc[7] += v * g1.w;
    }
    #pragma unroll
    for (int e = 0; e < NE; e++) {
        for (int off = 32; off > 0; off >>= 1)
            acc[e] += __shfl_down(acc[e], off, 64);
    }
    __shared__ float part[4][NE];
    int wave = tid >> 6, lane = tid & 63;
    if (lane == 0) {
        #pragma unroll
        for (int e = 0; e < NE; e++) part[wave][e] = acc[e];
    }
    __syncthreads();
    if (tid == 0) {
        float s[NE];
        #pragma unroll
        for (int e = 0; e < NE; e++)
            s[e] = part[0][e] + part[1][e] + part[2][e] + part[3][e] + gb[e];
        int amax = 0; float m = s[0];
        #pragma unroll
        for (int e = 1; e < NE; e++) if (s[e] > m) { m = s[e]; amax = e; }
        float denom = 0.f;
        #pragma unroll
        for (int e = 0; e < NE; e++) denom += expf(s[e] - m);
        gate_w[t] = 1.0f / denom;
        int pos = atomicAdd(&counts[amax], 1);
        tok_list[amax * NT + pos] = t;
    }
}

// ---------------- scheduler: dense (expert, m-tile) item list ----------------
__global__ void sched_kernel(const int* __restrict__ counts,
                             int* __restrict__ items, int* __restrict__ nitems)
{
    if (threadIdx.x == 0) {
        int k = 0;
        for (int e = 0; e < NE; e++) {
            int n = counts[e];
            int mt = (n + 63) >> 6;
            for (int m = 0; m < mt; m++) items[k++] = (e << 16) | m;
        }
        nitems[0] = k;
    }
}

// ---------------- x -> bf16 ----------------
__global__ __launch_bounds__(256) void convx_kernel(
    const float* __restrict__ xr, const float* __restrict__ xi,
    unsigned short* __restrict__ obr, unsigned short* __restrict__ obi)
{
    int i = blockIdx.x * 256 + threadIdx.x;
    float4 vr = ((const float4*)xr)[i];
    float4 vi = ((const float4*)xi)[i];
    ((ushort4*)obr)[i] = make_ushort4(f2bf(vr.x), f2bf(vr.y), f2bf(vr.z), f2bf(vr.w));
    ((ushort4*)obi)[i] = make_ushort4(f2bf(vi.x), f2bf(vi.y), f2bf(vi.z), f2bf(vi.w));
}

// ---------------- weight transpose + bf16: src fp32 [e][R][C] -> dst bf16 [e][C][R] ----
__global__ __launch_bounds__(256) void transw_kernel(
    const float* __restrict__ s0, unsigned short* __restrict__ d0,
    const float* __restrict__ s1, unsigned short* __restrict__ d1,
    int R, int C)
{
    __shared__ float tile[64][65];
    int e = blockIdx.z;
    int c0 = blockIdx.x * 64, r0 = blockIdx.y * 64;
    size_t off = (size_t)e * R * C;
    int tid = threadIdx.x;
    #pragma unroll
    for (int p = 0; p < 2; ++p) {
        const float* src = (p ? s1 : s0) + off;
        unsigned short* dst = (p ? d1 : d0) + off;
        if (p) __syncthreads();
        for (int i = 0; i < 16; ++i) {
            int idx = tid + i * 256;
            int r = idx >> 6, c = idx & 63;
            tile[r][c] = src[(size_t)(r0 + r) * C + c0 + c];
        }
        __syncthreads();
        #pragma unroll
        for (int i = 0; i < 4; ++i) {
            int c = i * 16 + (tid >> 4);
            int r4 = (tid & 15) * 4;
            ushort4 v = make_ushort4(f2bf(tile[r4][c]), f2bf(tile[r4 + 1][c]),
                                     f2bf(tile[r4 + 2][c]), f2bf(tile[r4 + 3][c]));
            *(ushort4*)&dst[(size_t)(c0 + c) * R + r0 + r4] = v;
        }
    }
}

// ---------------- shared GEMM machinery for moe1/moe2 ----------------
// A (tokens) -> LDS, double-buffered (4 x 8KB = 32KB). B (weights) are
// per-wave-private rows -> registers, prefetched one K-step ahead.
// Counted vmcnt: 4 GLL + 4 B-loads = 8 vmem/K-step; vmcnt(8) completes the
// current K-step's ops while the next K-step's 8 stay in flight.
// LDS XOR swizzle on A: physical k-chunk = logical ^ (row & 7), applied on
// the global-source side of GLL.

#define STAGEA_(SA_R, SA_I, ko) do {             \
    GLL(gAr0 + (ko), SA_R + (w * 16) * 64);      \
    GLL(gAi0 + (ko), SA_I + (w * 16) * 64);      \
    GLL(gAr1 + (ko), SA_R + (w * 16 + 8) * 64);  \
    GLL(gAi1 + (ko), SA_I + (w * 16 + 8) * 64);  \
} while (0)

#define LOADB_(r0, i0, r1, i1, kt) do {                      \
    r0 = *(const short8*)(gBr + (size_t)(kt) * 64);          \
    r1 = *(const short8*)(gBr + (size_t)(kt) * 64 + 32);     \
    i0 = *(const short8*)(gBi + (size_t)(kt) * 64);          \
    i1 = *(const short8*)(gBi + (size_t)(kt) * 64 + 32);     \
} while (0)

#define COMPUTE_(SA_R, SA_I, br0, bi0, br1, bi1) do {                                  \
    _Pragma("unroll")                                                                  \
    for (int ks = 0; ks < 2; ++ks) {                                                   \
        int pa = ((ks * 4 + quad) ^ (l15 & 7)) * 8;                                    \
        short8 br = ks ? br1 : br0;                                                    \
        short8 bi = ks ? bi1 : bi0;                                                    \
        _Pragma("unroll")                                                              \
        for (int m = 0; m < 4; ++m) {                                                  \
            short8 ar = lds8(SA_R + (m * 16 + l15) * 64 + pa);                         \
            short8 ai = lds8(SA_I + (m * 16 + l15) * 64 + pa);                         \
            short8 an = neg8(ai);                                                      \
            accr[m] = __builtin_amdgcn_mfma_f32_16x16x32_bf16(ar, br, accr[m], 0, 0, 0); \
            accr[m] = __builtin_amdgcn_mfma_f32_16x16x32_bf16(an, bi, accr[m], 0, 0, 0); \
            acci[m] = __builtin_amdgcn_mfma_f32_16x16x32_bf16(ar, bi, acci[m], 0, 0, 0); \
            acci[m] = __builtin_amdgcn_mfma_f32_16x16x32_bf16(ai, br, acci[m], 0, 0, 0); \
        }                                                                              \
    }                                                                                  \
} while (0)

#define VMW8  asm volatile("s_waitcnt vmcnt(8)" ::: "memory")
#define VMW0  asm volatile("s_waitcnt vmcnt(0)" ::: "memory")
#define BARX do {                            \
    __builtin_amdgcn_sched_barrier(0);       \
    __builtin_amdgcn_s_barrier();            \
    __builtin_amdgcn_sched_barrier(0);       \
} while (0)

// K-loop: NK = 8 K-steps of 64 for both moe1 (K=512) and moe2 (split-K=4, 512/slice)
#define PIPE8 do {                                                          \
    STAGEA_(sAr0, sAi0, 0);                                                 \
    LOADB_(b0r0, b0i0, b0r1, b0i1, 0);                                      \
    VMW0; BARX;                                                             \
    _Pragma("unroll 1")                                                     \
    for (int kt = 0; kt < 8; kt += 2) {                                     \
        if (kt + 1 < 8) {                                                   \
            STAGEA_(sAr1, sAi1, (kt + 1) * 64);                             \
            LOADB_(b1r0, b1i0, b1r1, b1i1, kt + 1);                         \
            VMW8;                                                           \
        } else VMW0;                                                        \
        BARX;                                                               \
        COMPUTE_(sAr0, sAi0, b0r0, b0i0, b0r1, b0i1);                       \
        BARX;                                                               \
        if (kt + 2 < 8) {                                                   \
            STAGEA_(sAr0, sAi0, (kt + 2) * 64);                             \
            LOADB_(b0r0, b0i0, b0r1, b0i1, kt + 2);                         \
            VMW8;                                                           \
        } else VMW0;                                                        \
        BARX;                                                               \
        COMPUTE_(sAr1, sAi1, b1r0, b1i0, b1r1, b1i1);                       \
        BARX;                                                               \
    }                                                                       \
} while (0)

#define MOE_LDS_DECL                                                        \
    __shared__ alignas(16) unsigned short sAr0[4096], sAi0[4096];           \
    __shared__ alignas(16) unsigned short sAr1[4096], sAi1[4096];           \
    __shared__ int s_u;

// ---------------- stage 1: complex D->H, persistent work-queue -> h bf16 ---
__global__ __launch_bounds__(256, 3) void moe1_kernel(
    const unsigned short* __restrict__ xbr, const unsigned short* __restrict__ xbi,
    const unsigned short* __restrict__ w1tr, const unsigned short* __restrict__ w1ti,
    const float* __restrict__ b1r, const float* __restrict__ b1i,
    const float* __restrict__ mod_b,
    const int* __restrict__ counts, const int* __restrict__ tok_list,
    const int* __restrict__ items, const int* __restrict__ nitems,
    int* __restrict__ q,
    unsigned short* __restrict__ hr, unsigned short* __restrict__ hi)
{
    int tid = threadIdx.x;
    int w = tid >> 6, l = tid & 63;
    int l15 = l & 15, quad = l >> 4;
    int swz = (((l & 7) ^ ((l >> 3) & 7)) * 8);

    MOE_LDS_DECL

    int total = nitems[0] * 32;   // items * 32 n-tiles

    for (;;) {
        __syncthreads();
        if (tid == 0) s_u = atomicAdd(q, 1);
        __syncthreads();
        int u = s_u;
        if (u >= total) return;

        int it = items[u >> 5];
        int nt = u & 31;
        int e = it >> 16, mt = it & 0xffff;
        int n = counts[e];
        int mbase = mt * 64, n0 = nt * 64;
        const int* tl = tok_list + e * NT;

        int ia0 = mbase + w * 16 + (l >> 3);
        int ia1 = ia0 + 8;
        int ra0 = tl[ia0 < n ? ia0 : n - 1];
        int ra1 = tl[ia1 < n ? ia1 : n - 1];
        const unsigned short* gAr0 = xbr + (size_t)ra0 * ND + swz;
        const unsigned short* gAi0 = xbi + (size_t)ra0 * ND + swz;
        const unsigned short* gAr1 = xbr + (size_t)ra1 * ND + swz;
        const unsigned short* gAi1 = xbi + (size_t)ra1 * ND + swz;
        const unsigned short* gBr = w1tr + ((size_t)e * NH + n0 + w * 16 + l15) * ND + quad * 8;
        const unsigned short* gBi = w1ti + ((size_t)e * NH + n0 + w * 16 + l15) * ND + quad * 8;

        f32x4 accr[4] = {}, acci[4] = {};
        short8 b0r0, b0i0, b0r1, b0i1, b1r0, b1i0, b1r1, b1i1;

        PIPE8;

        // epilogue: C/D layout col = lane&15 (N), row = quad*4 + r (M)
        int col = n0 + w * 16 + l15;
        float bre = b1r[(size_t)e * NH + col];
        float bie = b1i[(size_t)e * NH + col];
        float mbv = mod_b[(size_t)e * NH + col];
        #pragma unroll
        for (int m = 0; m < 4; ++m) {
            #pragma unroll
            for (int r = 0; r < 4; ++r) {
                int tix = m * 16 + quad * 4 + r;
                if (mbase + tix >= n) continue;
                int tok = tl[mbase + tix];
                float vr = accr[m][r] + bre;
                float vi = acci[m][r] + bie;
                float a = sqrtf(vr * vr + vi * vi + 1e-10f);
                float sc = fmaxf(a + mbv, 0.0f) / (a + 1e-10f);
                hr[(size_t)tok * NH + col] = f2bf(vr * sc);
                hi[(size_t)tok * NH + col] = f2bf(vi * sc);
            }
        }
    }
}

// ---------------- stage 2: complex H->D, split-K=4, persistent -> atomic out
__global__ __launch_bounds__(256, 3) void moe2_kernel(
    const unsigned short* __restrict__ hr, const unsigned short* __restrict__ hi,
    const unsigned short* __restrict__ w2tr, const unsigned short* __restrict__ w2ti,
    const float* __restrict__ b2r, const float* __restrict__ b2i,
    const int* __restrict__ counts, const int* __restrict__ tok_list,
    const int* __restrict__ items, const int* __restrict__ nitems,
    int* __restrict__ q,
    const float* __restrict__ gate_w,
    float* __restrict__ out)
{
    int tid = threadIdx.x;
    int w = tid >> 6, l = tid & 63;
    int l15 = l & 15, quad = l >> 4;
    int swz = (((l & 7) ^ ((l >> 3) & 7)) * 8);

    MOE_LDS_DECL

    int total = nitems[0] * 32;   // items * 8 n-tiles * 4 k-slices

    for (;;) {
        __syncthreads();
        if (tid == 0) s_u = atomicAdd(q, 1);
        __syncthreads();
        int u = s_u;
        if (u >= total) return;

        int it = items[u >> 5];
        int nt = u & 7;
        int ksl = (u >> 3) & 3;
        int e = it >> 16, mt = it & 0xffff;
        int n = counts[e];
        int mbase = mt * 64, n0 = nt * 64;
        int kbase = ksl * (NH / 4);
        const int* tl = tok_list + e * NT;

        int ia0 = mbase + w * 16 + (l >> 3);
        int ia1 = ia0 + 8;
        int ra0 = tl[ia0 < n ? ia0 : n - 1];
        int ra1 = tl[ia1 < n ? ia1 : n - 1];
        const unsigned short* gAr0 = hr + (size_t)ra0 * NH + kbase + swz;
        const unsigned short* gAi0 = hi + (size_t)ra0 * NH + kbase + swz;
        const unsigned short* gAr1 = hr + (size_t)ra1 * NH + kbase + swz;
        const unsigned short* gAi1 = hi + (size_t)ra1 * NH + kbase + swz;
        const unsigned short* gBr = w2tr + ((size_t)e * ND + n0 + w * 16 + l15) * NH + kbase + quad * 8;
        const unsigned short* gBi = w2ti + ((size_t)e * ND + n0 + w * 16 + l15) * NH + kbase + quad * 8;

        f32x4 accr[4] = {}, acci[4] = {};
        short8 b0r0, b0i0, b0r1, b0i1, b1r0, b1i0, b1r1, b1i1;

        PIPE8;

        int col = n0 + w * 16 + l15;
        float bre = (ksl == 0) ? b2r[(size_t)e * ND + col] : 0.0f;
        float bie = (ksl == 0) ? b2i[(size_t)e * ND + col] : 0.0f;
        #pragma unroll
        for (int m = 0; m < 4; ++m) {
            #pragma unroll
            for (int r = 0; r < 4; ++r) {
                int tix = m * 16 + quad * 4 + r;
                if (mbase + tix >= n) continue;
                int tok = tl[mbase + tix];
                float gw = gate_w[tok];
                atomicAdd(&out[(size_t)tok * ND + col], (accr[m][r] + bre) * gw);
                atomicAdd(&out[(size_t)NT * ND + (size_t)tok * ND + col], (acci[m][r] + bie) * gw);
            }
        }
    }
}

extern "C" void kernel_launch(void* const* d_in, const int* in_sizes, int n_in,
                              void* d_out, int out_size, void* d_ws, size_t ws_size,
                              hipStream_t stream) {
    const float* xr   = (const float*)d_in[0];
    const float* xi   = (const float*)d_in[1];
    const float* gW   = (const float*)d_in[2];
    const float* gb   = (const float*)d_in[3];
    const float* W1r  = (const float*)d_in[4];
    const float* W1i  = (const float*)d_in[5];
    const float* b1r  = (const float*)d_in[6];
    const float* b1i  = (const float*)d_in[7];
    const float* modb = (const float*)d_in[8];
    const float* W2r  = (const float*)d_in[9];
    const float* W2i  = (const float*)d_in[10];
    const float* b2r  = (const float*)d_in[11];
    const float* b2i  = (const float*)d_in[12];
    float* out = (float*)d_out;

    char* ws = (char*)d_ws;
    int*   counts   = (int*)ws;                              // 64 ints (memset): [0..7]=counts, [8]=q1, [9]=q2
    float* gate_w   = (float*)(ws + 256);                    // NT*4
    int*   tok_list = (int*)(ws + 256 + 8192);               // NE*NT*4
    size_t off = 256 + 8192 + (size_t)NE * NT * 4;
    int*   items    = (int*)(ws + off); off += 256;          // <=40 items + pad
    int*   nitems   = (int*)(ws + off); off += 256;
    unsigned short* xbr  = (unsigned short*)(ws + off); off += (size_t)NT * ND * 2;
    unsigned short* xbi  = (unsigned short*)(ws + off); off += (size_t)NT * ND * 2;
    unsigned short* w1tr = (unsigned short*)(ws + off); off += (size_t)NE * ND * NH * 2;
    unsigned short* w1ti = (unsigned short*)(ws + off); off += (size_t)NE * ND * NH * 2;
    unsigned short* w2tr = (unsigned short*)(ws + off); off += (size_t)NE * ND * NH * 2;
    unsigned short* w2ti = (unsigned short*)(ws + off); off += (size_t)NE * ND * NH * 2;
    unsigned short* h_r  = (unsigned short*)(ws + off); off += (size_t)NT * NH * 2;
    unsigned short* h_i  = (unsigned short*)(ws + off); off += (size_t)NT * NH * 2;

    int* q1 = counts + 8;
    int* q2 = counts + 9;

    hipMemsetAsync(counts, 0, 64 * sizeof(int), stream);
    hipMemsetAsync(out, 0, (size_t)out_size * sizeof(float), stream);
    gate_kernel<<<NT, 256, 0, stream>>>(xr, xi, gW, gb, gate_w, counts, tok_list);
    sched_kernel<<<1, 64, 0, stream>>>(counts, items, nitems);
    convx_kernel<<<(NT * ND / 4) / 256, 256, 0, stream>>>(xr, xi, xbr, xbi);
    transw_kernel<<<dim3(NH / 64, ND / 64, NE), 256, 0, stream>>>(W1r, w1tr, W1i, w1ti, ND, NH);
    transw_kernel<<<dim3(ND / 64, NH / 64, NE), 256, 0, stream>>>(W2r, w2tr, W2i, w2ti, NH, ND);
    moe1_kernel<<<768, 256, 0, stream>>>(
        xbr, xbi, w1tr, w1ti, b1r, b1i, modb, counts, tok_list, items, nitems, q1, h_r, h_i);
    moe2_kernel<<<768, 256, 0, stream>>>(
        h_r, h_i, w2tr, w2ti, b2r, b2i, counts, tok_list, items, nitems, q2, gate_w, out);
}

// Round 4
// 311.313 us; speedup vs baseline: 1.1228x; 1.1228x over previous
//
#include <hip/hip_runtime.h>
#include <math.h>

#define NE 8      // experts
#define ND 512    // features
#define NH 2048   // hidden
#define NT 2048   // tokens = B*S

typedef __attribute__((ext_vector_type(8))) short short8;   // 8 bf16 = 4 VGPRs
typedef __attribute__((ext_vector_type(4))) float f32x4;    // MFMA accumulator

#define GLL(g, d) __builtin_amdgcn_global_load_lds( \
    (const __attribute__((address_space(1))) void*)(g), \
    (__attribute__((address_space(3))) void*)(d), 16, 0, 0)

__device__ __forceinline__ unsigned short f2bf(float x) {
    unsigned int u = __builtin_bit_cast(unsigned int, x);
    u += 0x7FFFu + ((u >> 16) & 1u);            // round-to-nearest-even
    return (unsigned short)(u >> 16);
}

__device__ __forceinline__ short8 lds8(const unsigned short* p) {
    return *(const short8*)p;
}

// ---------------- gating (fp32, exact argmax semantics) + x->bf16 fused ----
__global__ __launch_bounds__(256) void gate_kernel(
    const float* __restrict__ xr, const float* __restrict__ xi,
    const float* __restrict__ gW, const float* __restrict__ gb,
    float* __restrict__ gate_w,
    int* __restrict__ counts, int* __restrict__ tok_list,
    unsigned short* __restrict__ obr, unsigned short* __restrict__ obi)
{
    int t = blockIdx.x;
    int tid = threadIdx.x;
    const float* xrt = xr + (size_t)t * ND;
    const float* xit = xi + (size_t)t * ND;

    // fused bf16 conversion of this token's row (L1-hot with the gating reads)
    #pragma unroll
    for (int d = tid; d < ND; d += 256) {
        obr[(size_t)t * ND + d] = f2bf(xrt[d]);
        obi[(size_t)t * ND + d] = f2bf(xit[d]);
    }

    float acc[NE] = {0,0,0,0,0,0,0,0};
    for (int r = tid; r < 2 * ND; r += 256) {
        int d = r & (ND - 1);
        float a = xrt[d], b = xit[d];
        float v = (r < ND) ? sqrtf(a * a + b * b) : atan2f(b, a);
        const float4* g = (const float4*)(gW + (size_t)r * NE);
        float4 g0 = g[0], g1 = g[1];
        acc[0] += v * g0.x; acc[1] += v * g0.y; acc[2] += v * g0.z; acc[3] += v * g0.w;
        acc[4] += v * g1.x; acc[5] += v * g1.y; acc[6] += v * g1.z; acc[7] += v * g1.w;
    }
    #pragma unroll
    for (int e = 0; e < NE; e++) {
        for (int off = 32; off > 0; off >>= 1)
            acc[e] += __shfl_down(acc[e], off, 64);
    }
    __shared__ float part[4][NE];
    int wave = tid >> 6, lane = tid & 63;
    if (lane == 0) {
        #pragma unroll
        for (int e = 0; e < NE; e++) part[wave][e] = acc[e];
    }
    __syncthreads();
    if (tid == 0) {
        float s[NE];
        #pragma unroll
        for (int e = 0; e < NE; e++)
            s[e] = part[0][e] + part[1][e] + part[2][e] + part[3][e] + gb[e];
        int amax = 0; float m = s[0];
        #pragma unroll
        for (int e = 1; e < NE; e++) if (s[e] > m) { m = s[e]; amax = e; }
        float denom = 0.f;
        #pragma unroll
        for (int e = 0; e < NE; e++) denom += expf(s[e] - m);
        gate_w[t] = 1.0f / denom;
        int pos = atomicAdd(&counts[amax], 1);
        tok_list[amax * NT + pos] = t;
    }
}

// ---------------- scheduler: dense (expert, m-tile) item list ----------------
__global__ void sched_kernel(const int* __restrict__ counts,
                             int* __restrict__ items, int* __restrict__ nitems)
{
    if (threadIdx.x == 0) {
        int k = 0;
        for (int e = 0; e < NE; e++) {
            int n = counts[e];
            int mt = (n + 63) >> 6;
            for (int m = 0; m < mt; m++) items[k++] = (e << 16) | m;
        }
        nitems[0] = k;
    }
}

// ---------------- weight transpose + bf16: src fp32 [e][R][C] -> dst bf16 [e][C][R] ----
__global__ __launch_bounds__(256) void transw_kernel(
    const float* __restrict__ s0, unsigned short* __restrict__ d0,
    const float* __restrict__ s1, unsigned short* __restrict__ d1,
    int R, int C)
{
    __shared__ float tile[64][65];
    int e = blockIdx.z;
    int c0 = blockIdx.x * 64, r0 = blockIdx.y * 64;
    size_t off = (size_t)e * R * C;
    int tid = threadIdx.x;
    #pragma unroll
    for (int p = 0; p < 2; ++p) {
        const float* src = (p ? s1 : s0) + off;
        unsigned short* dst = (p ? d1 : d0) + off;
        if (p) __syncthreads();
        for (int i = 0; i < 16; ++i) {
            int idx = tid + i * 256;
            int r = idx >> 6, c = idx & 63;
            tile[r][c] = src[(size_t)(r0 + r) * C + c0 + c];
        }
        __syncthreads();
        #pragma unroll
        for (int i = 0; i < 4; ++i) {
            int c = i * 16 + (tid >> 4);
            int r4 = (tid & 15) * 4;
            ushort4 v = make_ushort4(f2bf(tile[r4][c]), f2bf(tile[r4 + 1][c]),
                                     f2bf(tile[r4 + 2][c]), f2bf(tile[r4 + 3][c]));
            *(ushort4*)&dst[(size_t)(c0 + c) * R + r0 + r4] = v;
        }
    }
}

// ---------------- shared GEMM machinery for moe1/moe2 ----------------
// A and B staged via global_load_lds, double-buffered (8 x 8KB = 64KB, 2 blk/CU).
// Counted-vmcnt pipeline (verified trace): steady state keeps the next K-step's
// 8 loads in flight across both barriers and the compute phase; vmcnt(8) waits
// exactly the current step's 8 (oldest).
// LDS XOR swizzle: physical k-chunk = logical ^ (row & 7), applied on the
// global-source side of GLL (LDS slot order fixed to lane order).

#define STAGE_(SA_R, SA_I, SB_R, SB_I, ko) do {  \
    GLL(gAr0 + (ko), SA_R + (w * 16) * 64);      \
    GLL(gAi0 + (ko), SA_I + (w * 16) * 64);      \
    GLL(gAr1 + (ko), SA_R + (w * 16 + 8) * 64);  \
    GLL(gAi1 + (ko), SA_I + (w * 16 + 8) * 64);  \
    GLL(gBr0 + (ko), SB_R + (w * 16) * 64);      \
    GLL(gBr1 + (ko), SB_R + (w * 16 + 8) * 64);  \
    GLL(gBi0 + (ko), SB_I + (w * 16) * 64);      \
    GLL(gBi1 + (ko), SB_I + (w * 16 + 8) * 64);  \
} while (0)

// 4 independent accumulators (RR, II, RI, IR): no VALU in the hot loop,
// 16 independent MFMA dep chains. Combined in epilogue: r = RR-II, i = RI+IR.
#define COMPUTE_(SA_R, SA_I, SB_R, SB_I) do {                                          \
    _Pragma("unroll")                                                                  \
    for (int ks = 0; ks < 2; ++ks) {                                                   \
        int pa = ((ks * 4 + quad) ^ (l15 & 7)) * 8;                                    \
        short8 br  = lds8(SB_R + (w * 16 + l15) * 64 + pa);                            \
        short8 bi2 = lds8(SB_I + (w * 16 + l15) * 64 + pa);                            \
        _Pragma("unroll")                                                              \
        for (int m = 0; m < 4; ++m) {                                                  \
            short8 ar  = lds8(SA_R + (m * 16 + l15) * 64 + pa);                        \
            short8 ai2 = lds8(SA_I + (m * 16 + l15) * 64 + pa);                        \
            aRR[m] = __builtin_amdgcn_mfma_f32_16x16x32_bf16(ar,  br,  aRR[m], 0, 0, 0); \
            aII[m] = __builtin_amdgcn_mfma_f32_16x16x32_bf16(ai2, bi2, aII[m], 0, 0, 0); \
            aRI[m] = __builtin_amdgcn_mfma_f32_16x16x32_bf16(ar,  bi2, aRI[m], 0, 0, 0); \
            aIR[m] = __builtin_amdgcn_mfma_f32_16x16x32_bf16(ai2, br,  aIR[m], 0, 0, 0); \
        }                                                                              \
    }                                                                                  \
} while (0)

#define VMW8  asm volatile("s_waitcnt vmcnt(8)" ::: "memory")
#define VMW0  asm volatile("s_waitcnt vmcnt(0)" ::: "memory")
#define BARX do {                            \
    __builtin_amdgcn_sched_barrier(0);       \
    __builtin_amdgcn_s_barrier();            \
    __builtin_amdgcn_sched_barrier(0);       \
} while (0)

#define MOE_LDS_DECL                                                        \
    __shared__ alignas(16) unsigned short sAr0[4096], sAi0[4096];           \
    __shared__ alignas(16) unsigned short sBr0[4096], sBi0[4096];           \
    __shared__ alignas(16) unsigned short sAr1[4096], sAi1[4096];           \
    __shared__ alignas(16) unsigned short sBr1[4096], sBi1[4096];

#define PIPE_LOOP(NK) do {                                                  \
    STAGE_(sAr0, sAi0, sBr0, sBi0, 0);                                      \
    VMW0; BARX;                                                             \
    _Pragma("unroll 1")                                                     \
    for (int kt = 0; kt < (NK); kt += 2) {                                  \
        if (kt + 1 < (NK)) { STAGE_(sAr1, sAi1, sBr1, sBi1, (kt + 1) * 64); VMW8; } \
        else VMW0;                                                          \
        BARX;                                                               \
        COMPUTE_(sAr0, sAi0, sBr0, sBi0);                                   \
        BARX;                                                               \
        if (kt + 2 < (NK)) { STAGE_(sAr0, sAi0, sBr0, sBi0, (kt + 2) * 64); VMW8; } \
        else VMW0;                                                          \
        BARX;                                                               \
        COMPUTE_(sAr1, sAi1, sBr1, sBi1);                                   \
        BARX;                                                               \
    }                                                                       \
} while (0)

#define NBLK 512   // 2 blocks/CU x 256 CUs; chunked dense-unit assignment

// ---------------- stage 1: complex D->H, dense chunked units -> h bf16 ---
__global__ __launch_bounds__(256, 2) void moe1_kernel(
    const unsigned short* __restrict__ xbr, const unsigned short* __restrict__ xbi,
    const unsigned short* __restrict__ w1tr, const unsigned short* __restrict__ w1ti,
    const float* __restrict__ b1r, const float* __restrict__ b1i,
    const float* __restrict__ mod_b,
    const int* __restrict__ counts, const int* __restrict__ tok_list,
    const int* __restrict__ items, const int* __restrict__ nitems,
    unsigned short* __restrict__ hr, unsigned short* __restrict__ hi)
{
    int tid = threadIdx.x;
    int w = tid >> 6, l = tid & 63;
    int l15 = l & 15, quad = l >> 4;
    int swz = (((l & 7) ^ ((l >> 3) & 7)) * 8);

    MOE_LDS_DECL

    int total = nitems[0] * 32;                    // items * 32 n-tiles
    int chunk = (total + NBLK - 1) / NBLK;
    int u0 = blockIdx.x * chunk;
    int u1 = u0 + chunk; if (u1 > total) u1 = total;

    for (int u = u0; u < u1; ++u) {
        int it = items[u >> 5];
        int nt = u & 31;
        int e = it >> 16, mt = it & 0xffff;
        int n = counts[e];
        int mbase = mt * 64, n0 = nt * 64;
        const int* tl = tok_list + e * NT;

        int ia0 = mbase + w * 16 + (l >> 3);
        int ia1 = ia0 + 8;
        int ra0 = tl[ia0 < n ? ia0 : n - 1];
        int ra1 = tl[ia1 < n ? ia1 : n - 1];
        const unsigned short* gAr0 = xbr + (size_t)ra0 * ND + swz;
        const unsigned short* gAi0 = xbi + (size_t)ra0 * ND + swz;
        const unsigned short* gAr1 = xbr + (size_t)ra1 * ND + swz;
        const unsigned short* gAi1 = xbi + (size_t)ra1 * ND + swz;
        size_t brow = (size_t)e * NH + n0 + w * 16 + (l >> 3);
        const unsigned short* gBr0 = w1tr + brow * ND + swz;
        const unsigned short* gBr1 = w1tr + (brow + 8) * ND + swz;
        const unsigned short* gBi0 = w1ti + brow * ND + swz;
        const unsigned short* gBi1 = w1ti + (brow + 8) * ND + swz;

        f32x4 aRR[4] = {}, aII[4] = {}, aRI[4] = {}, aIR[4] = {};

        PIPE_LOOP(ND / 64);   // 8 K-steps

        // epilogue: C/D layout col = lane&15 (N), row = quad*4 + r (M)
        int col = n0 + w * 16 + l15;
        float bre = b1r[(size_t)e * NH + col];
        float bie = b1i[(size_t)e * NH + col];
        float mbv = mod_b[(size_t)e * NH + col];
        #pragma unroll
        for (int m = 0; m < 4; ++m) {
            #pragma unroll
            for (int r = 0; r < 4; ++r) {
                int tix = m * 16 + quad * 4 + r;
                if (mbase + tix >= n) continue;
                int tok = tl[mbase + tix];
                float vr = aRR[m][r] - aII[m][r] + bre;
                float vi = aRI[m][r] + aIR[m][r] + bie;
                float a = sqrtf(vr * vr + vi * vi + 1e-10f);
                float sc = fmaxf(a + mbv, 0.0f) / (a + 1e-10f);
                hr[(size_t)tok * NH + col] = f2bf(vr * sc);
                hi[(size_t)tok * NH + col] = f2bf(vi * sc);
            }
        }
    }
}

// ---------------- stage 2: complex H->D, FULL K=2048, plain stores ---------
// Top-1 routing => each (token,col) owned by exactly one block => no atomics,
// no output memset. 32 K-steps amortize prologue/epilogue 4x vs split-K=4.
__global__ __launch_bounds__(256, 2) void moe2_kernel(
    const unsigned short* __restrict__ hr, const unsigned short* __restrict__ hi,
    const unsigned short* __restrict__ w2tr, const unsigned short* __restrict__ w2ti,
    const float* __restrict__ b2r, const float* __restrict__ b2i,
    const int* __restrict__ counts, const int* __restrict__ tok_list,
    const int* __restrict__ items, const int* __restrict__ nitems,
    const float* __restrict__ gate_w,
    float* __restrict__ out)
{
    int tid = threadIdx.x;
    int w = tid >> 6, l = tid & 63;
    int l15 = l & 15, quad = l >> 4;
    int swz = (((l & 7) ^ ((l >> 3) & 7)) * 8);

    MOE_LDS_DECL

    int total = nitems[0] * 8;                     // items * 8 n-tiles
    int chunk = (total + NBLK - 1) / NBLK;
    int u0 = blockIdx.x * chunk;
    int u1 = u0 + chunk; if (u1 > total) u1 = total;

    for (int u = u0; u < u1; ++u) {
        int it = items[u >> 3];
        int nt = u & 7;
        int e = it >> 16, mt = it & 0xffff;
        int n = counts[e];
        int mbase = mt * 64, n0 = nt * 64;
        const int* tl = tok_list + e * NT;

        int ia0 = mbase + w * 16 + (l >> 3);
        int ia1 = ia0 + 8;
        int ra0 = tl[ia0 < n ? ia0 : n - 1];
        int ra1 = tl[ia1 < n ? ia1 : n - 1];
        const unsigned short* gAr0 = hr + (size_t)ra0 * NH + swz;
        const unsigned short* gAi0 = hi + (size_t)ra0 * NH + swz;
        const unsigned short* gAr1 = hr + (size_t)ra1 * NH + swz;
        const unsigned short* gAi1 = hi + (size_t)ra1 * NH + swz;
        size_t brow = (size_t)e * ND + n0 + w * 16 + (l >> 3);
        const unsigned short* gBr0 = w2tr + brow * NH + swz;
        const unsigned short* gBr1 = w2tr + (brow + 8) * NH + swz;
        const unsigned short* gBi0 = w2ti + brow * NH + swz;
        const unsigned short* gBi1 = w2ti + (brow + 8) * NH + swz;

        f32x4 aRR[4] = {}, aII[4] = {}, aRI[4] = {}, aIR[4] = {};

        PIPE_LOOP(NH / 64);   // 32 K-steps, full K

        int col = n0 + w * 16 + l15;
        float bre = b2r[(size_t)e * ND + col];
        float bie = b2i[(size_t)e * ND + col];
        #pragma unroll
        for (int m = 0; m < 4; ++m) {
            #pragma unroll
            for (int r = 0; r < 4; ++r) {
                int tix = m * 16 + quad * 4 + r;
                if (mbase + tix >= n) continue;
                int tok = tl[mbase + tix];
                float gw = gate_w[tok];
                out[(size_t)tok * ND + col] = (aRR[m][r] - aII[m][r] + bre) * gw;
                out[(size_t)NT * ND + (size_t)tok * ND + col] = (aRI[m][r] + aIR[m][r] + bie) * gw;
            }
        }
    }
}

extern "C" void kernel_launch(void* const* d_in, const int* in_sizes, int n_in,
                              void* d_out, int out_size, void* d_ws, size_t ws_size,
                              hipStream_t stream) {
    const float* xr   = (const float*)d_in[0];
    const float* xi   = (const float*)d_in[1];
    const float* gW   = (const float*)d_in[2];
    const float* gb   = (const float*)d_in[3];
    const float* W1r  = (const float*)d_in[4];
    const float* W1i  = (const float*)d_in[5];
    const float* b1r  = (const float*)d_in[6];
    const float* b1i  = (const float*)d_in[7];
    const float* modb = (const float*)d_in[8];
    const float* W2r  = (const float*)d_in[9];
    const float* W2i  = (const float*)d_in[10];
    const float* b2r  = (const float*)d_in[11];
    const float* b2i  = (const float*)d_in[12];
    float* out = (float*)d_out;

    char* ws = (char*)d_ws;
    int*   counts   = (int*)ws;                              // 64 ints (memset)
    float* gate_w   = (float*)(ws + 256);                    // NT*4
    int*   tok_list = (int*)(ws + 256 + 8192);               // NE*NT*4
    size_t off = 256 + 8192 + (size_t)NE * NT * 4;
    int*   items    = (int*)(ws + off); off += 256;          // <=40 items + pad
    int*   nitems   = (int*)(ws + off); off += 256;
    unsigned short* xbr  = (unsigned short*)(ws + off); off += (size_t)NT * ND * 2;
    unsigned short* xbi  = (unsigned short*)(ws + off); off += (size_t)NT * ND * 2;
    unsigned short* w1tr = (unsigned short*)(ws + off); off += (size_t)NE * ND * NH * 2;
    unsigned short* w1ti = (unsigned short*)(ws + off); off += (size_t)NE * ND * NH * 2;
    unsigned short* w2tr = (unsigned short*)(ws + off); off += (size_t)NE * ND * NH * 2;
    unsigned short* w2ti = (unsigned short*)(ws + off); off += (size_t)NE * ND * NH * 2;
    unsigned short* h_r  = (unsigned short*)(ws + off); off += (size_t)NT * NH * 2;
    unsigned short* h_i  = (unsigned short*)(ws + off); off += (size_t)NT * NH * 2;

    hipMemsetAsync(counts, 0, 64 * sizeof(int), stream);
    gate_kernel<<<NT, 256, 0, stream>>>(xr, xi, gW, gb, gate_w, counts, tok_list, xbr, xbi);
    sched_kernel<<<1, 64, 0, stream>>>(counts, items, nitems);
    transw_kernel<<<dim3(NH / 64, ND / 64, NE), 256, 0, stream>>>(W1r, w1tr, W1i, w1ti, ND, NH);
    transw_kernel<<<dim3(ND / 64, NH / 64, NE), 256, 0, stream>>>(W2r, w2tr, W2i, w2ti, NH, ND);
    moe1_kernel<<<NBLK, 256, 0, stream>>>(
        xbr, xbi, w1tr, w1ti, b1r, b1i, modb, counts, tok_list, items, nitems, h_r, h_i);
    moe2_kernel<<<NBLK, 256, 0, stream>>>(
        h_r, h_i, w2tr, w2ti, b2r, b2i, counts, tok_list, items, nitems, gate_w, out);
}

// Round 5
// 297.648 us; speedup vs baseline: 1.1744x; 1.0459x over previous
//
#include <hip/hip_runtime.h>
#include <math.h>

#define NE 8      // experts
#define ND 512    // features
#define NH 2048   // hidden
#define NT 2048   // tokens = B*S
#define MAXIT 40  // max (expert, m-tile) items: 2048/64 + 8 partials

typedef __attribute__((ext_vector_type(8))) short short8;   // 8 bf16 = 4 VGPRs
typedef __attribute__((ext_vector_type(4))) float f32x4;    // MFMA accumulator

#define GLL(g, d) __builtin_amdgcn_global_load_lds( \
    (const __attribute__((address_space(1))) void*)(g), \
    (__attribute__((address_space(3))) void*)(d), 16, 0, 0)

__device__ __forceinline__ unsigned short f2bf(float x) {
    unsigned int u = __builtin_bit_cast(unsigned int, x);
    u += 0x7FFFu + ((u >> 16) & 1u);            // round-to-nearest-even
    return (unsigned short)(u >> 16);
}

__device__ __forceinline__ short8 lds8(const unsigned short* p) {
    return *(const short8*)p;
}

// ---------------- gating (fp32, exact argmax semantics) + x->bf16 fused ----
__global__ __launch_bounds__(256) void gate_kernel(
    const float* __restrict__ xr, const float* __restrict__ xi,
    const float* __restrict__ gW, const float* __restrict__ gb,
    float* __restrict__ gate_w,
    int* __restrict__ counts, int* __restrict__ tok_list,
    unsigned short* __restrict__ obr, unsigned short* __restrict__ obi)
{
    int t = blockIdx.x;
    int tid = threadIdx.x;
    const float* xrt = xr + (size_t)t * ND;
    const float* xit = xi + (size_t)t * ND;

    // fused bf16 conversion of this token's row (L1-hot with the gating reads)
    #pragma unroll
    for (int d = tid; d < ND; d += 256) {
        obr[(size_t)t * ND + d] = f2bf(xrt[d]);
        obi[(size_t)t * ND + d] = f2bf(xit[d]);
    }

    float acc[NE] = {0,0,0,0,0,0,0,0};
    for (int r = tid; r < 2 * ND; r += 256) {
        int d = r & (ND - 1);
        float a = xrt[d], b = xit[d];
        float v = (r < ND) ? sqrtf(a * a + b * b) : atan2f(b, a);
        const float4* g = (const float4*)(gW + (size_t)r * NE);
        float4 g0 = g[0], g1 = g[1];
        acc[0] += v * g0.x; acc[1] += v * g0.y; acc[2] += v * g0.z; acc[3] += v * g0.w;
        acc[4] += v * g1.x; acc[5] += v * g1.y; acc[6] += v * g1.z; acc[7] += v * g1.w;
    }
    #pragma unroll
    for (int e = 0; e < NE; e++) {
        for (int off = 32; off > 0; off >>= 1)
            acc[e] += __shfl_down(acc[e], off, 64);
    }
    __shared__ float part[4][NE];
    int wave = tid >> 6, lane = tid & 63;
    if (lane == 0) {
        #pragma unroll
        for (int e = 0; e < NE; e++) part[wave][e] = acc[e];
    }
    __syncthreads();
    if (tid == 0) {
        float s[NE];
        #pragma unroll
        for (int e = 0; e < NE; e++)
            s[e] = part[0][e] + part[1][e] + part[2][e] + part[3][e] + gb[e];
        int amax = 0; float m = s[0];
        #pragma unroll
        for (int e = 1; e < NE; e++) if (s[e] > m) { m = s[e]; amax = e; }
        float denom = 0.f;
        #pragma unroll
        for (int e = 0; e < NE; e++) denom += expf(s[e] - m);
        gate_w[t] = 1.0f / denom;
        int pos = atomicAdd(&counts[amax], 1);
        tok_list[amax * NT + pos] = t;
    }
}

// ---------------- weight transpose + bf16: src fp32 [e][R][C] -> dst bf16 [e][C][R] ----
// v2: float4 loads (16B/lane), bf16 convert BEFORE LDS, LDS tile stored
// transposed (9.2 KB, 8 blocks/CU), contiguous ds_read_b128 + short8 stores.
// zero_counts: first launch's block 0 zeroes the gating counters (replaces a
// hipMemsetAsync dispatch; stream order guarantees completion before gate).
__global__ __launch_bounds__(256) void transw_kernel(
    const float* __restrict__ s0, unsigned short* __restrict__ d0,
    const float* __restrict__ s1, unsigned short* __restrict__ d1,
    int R, int C, int* __restrict__ counts, int zero_counts)
{
    __shared__ unsigned short t[64][72];   // [col][row], +8 pad
    if (zero_counts && blockIdx.x == 0 && blockIdx.y == 0 && blockIdx.z == 0
        && threadIdx.x < 16)
        counts[threadIdx.x] = 0;
    int e = blockIdx.z;
    int c0 = blockIdx.x * 64, r0 = blockIdx.y * 64;
    size_t off = (size_t)e * R * C;
    int tid = threadIdx.x;
    #pragma unroll
    for (int p = 0; p < 2; ++p) {
        const float* src = (p ? s1 : s0) + off;
        unsigned short* dst = (p ? d1 : d0) + off;
        if (p) __syncthreads();
        #pragma unroll
        for (int i = 0; i < 4; ++i) {
            int r = i * 16 + (tid >> 4);
            int c4 = (tid & 15) * 4;
            float4 v = *(const float4*)&src[(size_t)(r0 + r) * C + c0 + c4];
            t[c4 + 0][r] = f2bf(v.x);
            t[c4 + 1][r] = f2bf(v.y);
            t[c4 + 2][r] = f2bf(v.z);
            t[c4 + 3][r] = f2bf(v.w);
        }
        __syncthreads();
        #pragma unroll
        for (int i = 0; i < 2; ++i) {
            int c = i * 32 + (tid >> 3);
            int r8 = (tid & 7) * 8;
            short8 v = *(const short8*)&t[c][r8];
            *(short8*)&dst[(size_t)(c0 + c) * R + r0 + r8] = v;
        }
    }
}

// ---------------- shared GEMM machinery for moe1/moe2 ----------------
// A and B staged via global_load_lds, double-buffered (8 x 8KB = 64KB, 2 blk/CU).
// Counted-vmcnt pipeline: steady state keeps the next K-step's 8 loads in
// flight across both barriers and the compute phase; vmcnt(8) waits exactly
// the current step's 8 (oldest). setprio(1) wraps the MFMA cluster (T5):
// co-resident blocks are at independent phases, scheduler favors compute.
// LDS XOR swizzle: physical k-chunk = logical ^ (row & 7), applied on the
// global-source side of GLL (LDS slot order fixed to lane order).

#define STAGE_(SA_R, SA_I, SB_R, SB_I, ko) do {  \
    GLL(gAr0 + (ko), SA_R + (w * 16) * 64);      \
    GLL(gAi0 + (ko), SA_I + (w * 16) * 64);      \
    GLL(gAr1 + (ko), SA_R + (w * 16 + 8) * 64);  \
    GLL(gAi1 + (ko), SA_I + (w * 16 + 8) * 64);  \
    GLL(gBr0 + (ko), SB_R + (w * 16) * 64);      \
    GLL(gBr1 + (ko), SB_R + (w * 16 + 8) * 64);  \
    GLL(gBi0 + (ko), SB_I + (w * 16) * 64);      \
    GLL(gBi1 + (ko), SB_I + (w * 16 + 8) * 64);  \
} while (0)

// 4 independent accumulators (RR, II, RI, IR): no VALU in the hot loop,
// 16 independent MFMA dep chains. Combined in epilogue: r = RR-II, i = RI+IR.
#define COMPUTE_(SA_R, SA_I, SB_R, SB_I) do {                                          \
    _Pragma("unroll")                                                                  \
    for (int ks = 0; ks < 2; ++ks) {                                                   \
        int pa = ((ks * 4 + quad) ^ (l15 & 7)) * 8;                                    \
        short8 br  = lds8(SB_R + (w * 16 + l15) * 64 + pa);                            \
        short8 bi2 = lds8(SB_I + (w * 16 + l15) * 64 + pa);                            \
        _Pragma("unroll")                                                              \
        for (int m = 0; m < 4; ++m) {                                                  \
            short8 ar  = lds8(SA_R + (m * 16 + l15) * 64 + pa);                        \
            short8 ai2 = lds8(SA_I + (m * 16 + l15) * 64 + pa);                        \
            aRR[m] = __builtin_amdgcn_mfma_f32_16x16x32_bf16(ar,  br,  aRR[m], 0, 0, 0); \
            aII[m] = __builtin_amdgcn_mfma_f32_16x16x32_bf16(ai2, bi2, aII[m], 0, 0, 0); \
            aRI[m] = __builtin_amdgcn_mfma_f32_16x16x32_bf16(ar,  bi2, aRI[m], 0, 0, 0); \
            aIR[m] = __builtin_amdgcn_mfma_f32_16x16x32_bf16(ai2, br,  aIR[m], 0, 0, 0); \
        }                                                                              \
    }                                                                                  \
} while (0)

#define VMW8  asm volatile("s_waitcnt vmcnt(8)" ::: "memory")
#define VMW0  asm volatile("s_waitcnt vmcnt(0)" ::: "memory")
#define BARX do {                            \
    __builtin_amdgcn_sched_barrier(0);       \
    __builtin_amdgcn_s_barrier();            \
    __builtin_amdgcn_sched_barrier(0);       \
} while (0)

#define MOE_LDS_DECL                                                        \
    __shared__ alignas(16) unsigned short sAr0[4096], sAi0[4096];           \
    __shared__ alignas(16) unsigned short sBr0[4096], sBi0[4096];           \
    __shared__ alignas(16) unsigned short sAr1[4096], sAi1[4096];           \
    __shared__ alignas(16) unsigned short sBr1[4096], sBi1[4096];

#define PIPE_LOOP(NK) do {                                                  \
    STAGE_(sAr0, sAi0, sBr0, sBi0, 0);                                      \
    VMW0; BARX;                                                             \
    _Pragma("unroll 1")                                                     \
    for (int kt = 0; kt < (NK); kt += 2) {                                  \
        if (kt + 1 < (NK)) { STAGE_(sAr1, sAi1, sBr1, sBi1, (kt + 1) * 64); VMW8; } \
        else VMW0;                                                          \
        BARX;                                                               \
        __builtin_amdgcn_s_setprio(1);                                      \
        COMPUTE_(sAr0, sAi0, sBr0, sBi0);                                   \
        __builtin_amdgcn_s_setprio(0);                                      \
        BARX;                                                               \
        if (kt + 2 < (NK)) { STAGE_(sAr0, sAi0, sBr0, sBi0, (kt + 2) * 64); VMW8; } \
        else VMW0;                                                          \
        BARX;                                                               \
        __builtin_amdgcn_s_setprio(1);                                      \
        COMPUTE_(sAr1, sAi1, sBr1, sBi1);                                   \
        __builtin_amdgcn_s_setprio(0);                                      \
        BARX;                                                               \
    }                                                                       \
} while (0)

// item derivation: block's item index -> (expert e, m-tile mt) via prefix
// scan over ceil(counts[e]/64). Returns false if item beyond total work.
__device__ __forceinline__ bool find_item(const int* counts, int item,
                                          int& e, int& mt, int& n) {
    int rem = item;
    for (e = 0; e < NE; ++e) {
        n = counts[e];
        int m = (n + 63) >> 6;
        if (rem < m) { mt = rem; return true; }
        rem -= m;
    }
    return false;
}

// ---------------- stage 1: complex D->H, one 64x64 unit per block -> h bf16 -
__global__ __launch_bounds__(256, 2) void moe1_kernel(
    const unsigned short* __restrict__ xbr, const unsigned short* __restrict__ xbi,
    const unsigned short* __restrict__ w1tr, const unsigned short* __restrict__ w1ti,
    const float* __restrict__ b1r, const float* __restrict__ b1i,
    const float* __restrict__ mod_b,
    const int* __restrict__ counts, const int* __restrict__ tok_list,
    unsigned short* __restrict__ hr, unsigned short* __restrict__ hi)
{
    int e, mt, n;
    if (!find_item(counts, blockIdx.x >> 5, e, mt, n)) return;
    int nt = blockIdx.x & 31;
    int mbase = mt * 64, n0 = nt * 64;

    int tid = threadIdx.x;
    int w = tid >> 6, l = tid & 63;
    int l15 = l & 15, quad = l >> 4;
    int swz = (((l & 7) ^ ((l >> 3) & 7)) * 8);

    MOE_LDS_DECL

    const int* tl = tok_list + e * NT;
    int ia0 = mbase + w * 16 + (l >> 3);
    int ia1 = ia0 + 8;
    int ra0 = tl[ia0 < n ? ia0 : n - 1];
    int ra1 = tl[ia1 < n ? ia1 : n - 1];
    const unsigned short* gAr0 = xbr + (size_t)ra0 * ND + swz;
    const unsigned short* gAi0 = xbi + (size_t)ra0 * ND + swz;
    const unsigned short* gAr1 = xbr + (size_t)ra1 * ND + swz;
    const unsigned short* gAi1 = xbi + (size_t)ra1 * ND + swz;
    size_t brow = (size_t)e * NH + n0 + w * 16 + (l >> 3);
    const unsigned short* gBr0 = w1tr + brow * ND + swz;
    const unsigned short* gBr1 = w1tr + (brow + 8) * ND + swz;
    const unsigned short* gBi0 = w1ti + brow * ND + swz;
    const unsigned short* gBi1 = w1ti + (brow + 8) * ND + swz;

    f32x4 aRR[4] = {}, aII[4] = {}, aRI[4] = {}, aIR[4] = {};

    PIPE_LOOP(ND / 64);   // 8 K-steps

    // epilogue: C/D layout col = lane&15 (N), row = quad*4 + r (M)
    int col = n0 + w * 16 + l15;
    float bre = b1r[(size_t)e * NH + col];
    float bie = b1i[(size_t)e * NH + col];
    float mbv = mod_b[(size_t)e * NH + col];
    #pragma unroll
    for (int m = 0; m < 4; ++m) {
        #pragma unroll
        for (int r = 0; r < 4; ++r) {
            int tix = m * 16 + quad * 4 + r;
            if (mbase + tix >= n) continue;
            int tok = tl[mbase + tix];
            float vr = aRR[m][r] - aII[m][r] + bre;
            float vi = aRI[m][r] + aIR[m][r] + bie;
            float a = sqrtf(vr * vr + vi * vi + 1e-10f);
            float sc = fmaxf(a + mbv, 0.0f) / (a + 1e-10f);
            hr[(size_t)tok * NH + col] = f2bf(vr * sc);
            hi[(size_t)tok * NH + col] = f2bf(vi * sc);
        }
    }
}

// ---------------- stage 2: complex H->D, FULL K=2048, plain stores ---------
// Top-1 routing => each (token,col) owned by exactly one block => no atomics.
__global__ __launch_bounds__(256, 2) void moe2_kernel(
    const unsigned short* __restrict__ hr, const unsigned short* __restrict__ hi,
    const unsigned short* __restrict__ w2tr, const unsigned short* __restrict__ w2ti,
    const float* __restrict__ b2r, const float* __restrict__ b2i,
    const int* __restrict__ counts, const int* __restrict__ tok_list,
    const float* __restrict__ gate_w,
    float* __restrict__ out)
{
    int e, mt, n;
    if (!find_item(counts, blockIdx.x >> 3, e, mt, n)) return;
    int nt = blockIdx.x & 7;
    int mbase = mt * 64, n0 = nt * 64;

    int tid = threadIdx.x;
    int w = tid >> 6, l = tid & 63;
    int l15 = l & 15, quad = l >> 4;
    int swz = (((l & 7) ^ ((l >> 3) & 7)) * 8);

    MOE_LDS_DECL

    const int* tl = tok_list + e * NT;
    int ia0 = mbase + w * 16 + (l >> 3);
    int ia1 = ia0 + 8;
    int ra0 = tl[ia0 < n ? ia0 : n - 1];
    int ra1 = tl[ia1 < n ? ia1 : n - 1];
    const unsigned short* gAr0 = hr + (size_t)ra0 * NH + swz;
    const unsigned short* gAi0 = hi + (size_t)ra0 * NH + swz;
    const unsigned short* gAr1 = hr + (size_t)ra1 * NH + swz;
    const unsigned short* gAi1 = hi + (size_t)ra1 * NH + swz;
    size_t brow = (size_t)e * ND + n0 + w * 16 + (l >> 3);
    const unsigned short* gBr0 = w2tr + brow * NH + swz;
    const unsigned short* gBr1 = w2tr + (brow + 8) * NH + swz;
    const unsigned short* gBi0 = w2ti + brow * NH + swz;
    const unsigned short* gBi1 = w2ti + (brow + 8) * NH + swz;

    f32x4 aRR[4] = {}, aII[4] = {}, aRI[4] = {}, aIR[4] = {};

    PIPE_LOOP(NH / 64);   // 32 K-steps, full K

    int col = n0 + w * 16 + l15;
    float bre = b2r[(size_t)e * ND + col];
    float bie = b2i[(size_t)e * ND + col];
    #pragma unroll
    for (int m = 0; m < 4; ++m) {
        #pragma unroll
        for (int r = 0; r < 4; ++r) {
            int tix = m * 16 + quad * 4 + r;
            if (mbase + tix >= n) continue;
            int tok = tl[mbase + tix];
            float gw = gate_w[tok];
            out[(size_t)tok * ND + col] = (aRR[m][r] - aII[m][r] + bre) * gw;
            out[(size_t)NT * ND + (size_t)tok * ND + col] = (aRI[m][r] + aIR[m][r] + bie) * gw;
        }
    }
}

extern "C" void kernel_launch(void* const* d_in, const int* in_sizes, int n_in,
                              void* d_out, int out_size, void* d_ws, size_t ws_size,
                              hipStream_t stream) {
    const float* xr   = (const float*)d_in[0];
    const float* xi   = (const float*)d_in[1];
    const float* gW   = (const float*)d_in[2];
    const float* gb   = (const float*)d_in[3];
    const float* W1r  = (const float*)d_in[4];
    const float* W1i  = (const float*)d_in[5];
    const float* b1r  = (const float*)d_in[6];
    const float* b1i  = (const float*)d_in[7];
    const float* modb = (const float*)d_in[8];
    const float* W2r  = (const float*)d_in[9];
    const float* W2i  = (const float*)d_in[10];
    const float* b2r  = (const float*)d_in[11];
    const float* b2i  = (const float*)d_in[12];
    float* out = (float*)d_out;

    char* ws = (char*)d_ws;
    int*   counts   = (int*)ws;                              // zeroed by transw1 block 0
    float* gate_w   = (float*)(ws + 256);                    // NT*4
    int*   tok_list = (int*)(ws + 256 + 8192);               // NE*NT*4
    size_t off = 256 + 8192 + (size_t)NE * NT * 4;
    unsigned short* xbr  = (unsigned short*)(ws + off); off += (size_t)NT * ND * 2;
    unsigned short* xbi  = (unsigned short*)(ws + off); off += (size_t)NT * ND * 2;
    unsigned short* w1tr = (unsigned short*)(ws + off); off += (size_t)NE * ND * NH * 2;
    unsigned short* w1ti = (unsigned short*)(ws + off); off += (size_t)NE * ND * NH * 2;
    unsigned short* w2tr = (unsigned short*)(ws + off); off += (size_t)NE * ND * NH * 2;
    unsigned short* w2ti = (unsigned short*)(ws + off); off += (size_t)NE * ND * NH * 2;
    unsigned short* h_r  = (unsigned short*)(ws + off); off += (size_t)NT * NH * 2;
    unsigned short* h_i  = (unsigned short*)(ws + off); off += (size_t)NT * NH * 2;

    // transw first (independent of gating); block 0 of the first launch zeroes
    // counts — stream order guarantees visibility before gate_kernel.
    transw_kernel<<<dim3(NH / 64, ND / 64, NE), 256, 0, stream>>>(
        W1r, w1tr, W1i, w1ti, ND, NH, counts, 1);
    transw_kernel<<<dim3(ND / 64, NH / 64, NE), 256, 0, stream>>>(
        W2r, w2tr, W2i, w2ti, NH, ND, counts, 0);
    gate_kernel<<<NT, 256, 0, stream>>>(xr, xi, gW, gb, gate_w, counts, tok_list, xbr, xbi);
    moe1_kernel<<<MAXIT * 32, 256, 0, stream>>>(
        xbr, xbi, w1tr, w1ti, b1r, b1i, modb, counts, tok_list, h_r, h_i);
    moe2_kernel<<<MAXIT * 8, 256, 0, stream>>>(
        h_r, h_i, w2tr, w2ti, b2r, b2i, counts, tok_list, gate_w, out);
}